// Round 5
// baseline (210.063 us; speedup 1.0000x reference)
//
#include <hip/hip_runtime.h>
#include <stdint.h>

#define B_N   8
#define C_N   256
#define H_N   96
#define W_N   128
#define NCK   8          // C_N / 32
#define ND    21
#define NK    (ND * ND)  // 441

typedef __attribute__((ext_vector_type(8))) short short8;
typedef __attribute__((ext_vector_type(4))) float f32x4;

// 12-KB zero block (.bss) for OOB dy rows
__device__ char zchunk[12288];

__device__ __forceinline__ uint32_t f2bf(float f) {
  uint32_t u = __builtin_bit_cast(uint32_t, f);
  return (u + 0x7fffu + ((u >> 16) & 1u)) >> 16;   // RNE
}
__device__ __forceinline__ uint32_t packbf(float lo, float hi) {
  return f2bf(lo) | (f2bf(hi) << 16);
}

// ---------------- merged prepass: fp32 NCHW -> bf16 fragment-linear layouts ----------------
__global__ __launch_bounds__(256) void prep(const float* __restrict__ in1,
                                            const float* __restrict__ in2,
                                            unsigned short* __restrict__ Apre,
                                            unsigned short* __restrict__ Bpre) {
  __shared__ float tile[32][W_N + 1];
  int blk = blockIdx.x;
  bool isA = blk < 6144;
  int rblk = isA ? blk : blk - 6144;
  int ck = rblk & 7, bi = rblk >> 3;
  int b = bi / H_N, row = bi % H_N;
  const float* src = (isA ? in1 : in2) + ((size_t)(b * C_N + ck * 32) * H_N + row) * W_N;
  int tid = threadIdx.x;
  for (int idx = tid; idx < 32 * W_N; idx += 256) {
    int c = idx >> 7, j = idx & 127;
    tile[c][j] = src[(size_t)c * (H_N * W_N) + j];
  }
  __syncthreads();
  if (isA) {
    uint32_t* dst = (uint32_t*)Apre + (size_t)rblk * 2048;
    for (int q = tid; q < 2048; q += 256) {
      int e2 = q & 3, ln = (q >> 2) & 63, tp = q >> 8;
      int t = tp >> 1, p = tp & 1;
      int m = ln & 15, kg = ln >> 4;
      int c0 = kg * 8 + 2 * e2;
      int j = 32 * t + 2 * m + p;
      dst[q] = packbf(tile[c0][j], tile[c0 + 1][j]);
    }
  } else {
    uint32_t* dst = (uint32_t*)Bpre + (size_t)rblk * 3072;
    for (int q = tid; q < 3072; q += 256) {
      int e2 = q & 3, ln = (q >> 2) & 63, sp = q >> 8;
      int s = sp >> 1, p = sp & 1;
      int m = ln & 15, kg = ln >> 4;
      int c0 = kg * 8 + 2 * e2;
      int x = 32 * s + 2 * m - 20 + p;
      dst[q] = ((unsigned)x < 128u) ? packbf(tile[c0][x], tile[c0 + 1][x]) : 0u;
    }
  }
}

// ---- fragment set: one chunk's worth of MFMA operands (56 VGPR) ----
#define DECL_FRAGS(F) short8 F##_a0, F##_a1, F##_bb0, F##_bb1, F##_bb2, F##_bb3, \
                             F##_bb4, F##_bb5, F##_bb6, F##_bb7, F##_bb8, F##_bb9, F##_bb10, F##_bb11

#define LOADF(F, CK) do {                                                        \
  F##_a0 = *(const short8*)(Ap + (size_t)(CK) * 8192);                           \
  F##_a1 = *(const short8*)(Ap + (size_t)(CK) * 8192 + 2048);                    \
  F##_bb0  = *(const short8*)(Bp0 + (size_t)(CK) * bstr0 + 0 * 2048);            \
  F##_bb1  = *(const short8*)(Bp1 + (size_t)(CK) * bstr1 + 0 * 2048);            \
  F##_bb2  = *(const short8*)(Bp2 + (size_t)(CK) * bstr2 + 0 * 2048);            \
  F##_bb3  = *(const short8*)(Bp0 + (size_t)(CK) * bstr0 + 1 * 2048);            \
  F##_bb4  = *(const short8*)(Bp1 + (size_t)(CK) * bstr1 + 1 * 2048);            \
  F##_bb5  = *(const short8*)(Bp2 + (size_t)(CK) * bstr2 + 1 * 2048);            \
  F##_bb6  = *(const short8*)(Bp0 + (size_t)(CK) * bstr0 + 2 * 2048);            \
  F##_bb7  = *(const short8*)(Bp1 + (size_t)(CK) * bstr1 + 2 * 2048);            \
  F##_bb8  = *(const short8*)(Bp2 + (size_t)(CK) * bstr2 + 2 * 2048);            \
  F##_bb9  = *(const short8*)(Bp0 + (size_t)(CK) * bstr0 + 3 * 2048);            \
  F##_bb10 = *(const short8*)(Bp1 + (size_t)(CK) * bstr1 + 3 * 2048);            \
  F##_bb11 = *(const short8*)(Bp2 + (size_t)(CK) * bstr2 + 3 * 2048);            \
} while (0)

#define MF(a, b, c) __builtin_amdgcn_mfma_f32_16x16x32_bf16(a, b, c, 0, 0, 0)
// 18 MFMAs: acc[tt][g][delta], delta = ss - tt, B frag index = ss*3+g
#define COMPUTE(F) do {                                                          \
  acc[0][0][0] = MF(F##_a0, F##_bb0,  acc[0][0][0]);                             \
  acc[0][1][0] = MF(F##_a0, F##_bb1,  acc[0][1][0]);                             \
  acc[0][2][0] = MF(F##_a0, F##_bb2,  acc[0][2][0]);                             \
  acc[0][0][1] = MF(F##_a0, F##_bb3,  acc[0][0][1]);                             \
  acc[1][0][0] = MF(F##_a1, F##_bb3,  acc[1][0][0]);                             \
  acc[0][1][1] = MF(F##_a0, F##_bb4,  acc[0][1][1]);                             \
  acc[1][1][0] = MF(F##_a1, F##_bb4,  acc[1][1][0]);                             \
  acc[0][2][1] = MF(F##_a0, F##_bb5,  acc[0][2][1]);                             \
  acc[1][2][0] = MF(F##_a1, F##_bb5,  acc[1][2][0]);                             \
  acc[0][0][2] = MF(F##_a0, F##_bb6,  acc[0][0][2]);                             \
  acc[1][0][1] = MF(F##_a1, F##_bb6,  acc[1][0][1]);                             \
  acc[0][1][2] = MF(F##_a0, F##_bb7,  acc[0][1][2]);                             \
  acc[1][1][1] = MF(F##_a1, F##_bb7,  acc[1][1][1]);                             \
  acc[0][2][2] = MF(F##_a0, F##_bb8,  acc[0][2][2]);                             \
  acc[1][2][1] = MF(F##_a1, F##_bb8,  acc[1][2][1]);                             \
  acc[1][0][2] = MF(F##_a1, F##_bb9,  acc[1][0][2]);                             \
  acc[1][1][2] = MF(F##_a1, F##_bb10, acc[1][1][2]);                             \
  acc[1][2][2] = MF(F##_a1, F##_bb11, acc[1][2][2]);                             \
} while (0)

// ---------------- main: barrier-free, register-double-buffered fragment pipeline ----------
__global__ __launch_bounds__(256, 2) void corr_main(const unsigned short* __restrict__ Apre,
                                                    const unsigned short* __restrict__ Bpre,
                                                    float* __restrict__ out) {
  __shared__ float outl[ND][W_N + 1];   // 10836 B epilogue buffer

  int h = blockIdx.x;
  int l = (h & 7) * 672 + (h >> 3);     // XCD-chunked remap (5376 = 8*672, bijective)
  int c = l / 7, q = l - 7 * c;         // chain, position (chain keeps B rows identical)
  int b = c / 96, i0 = c - 96 * b;
  int gidx = 6 - q;
  int i = i0 + 6 * q; if (i >= H_N) i -= H_N;
  int bi = b * H_N + i;
  int dyb = gidx * 3;

  int tid = threadIdx.x;
  int lane = tid & 63, w = tid >> 6;    // 4 waves: (parity p, t-half th)
  int p = w & 1, th = w >> 1;
  int m = lane & 15, kg = lane >> 4;

  f32x4 acc[2][3][3];
#pragma unroll
  for (int a0i = 0; a0i < 2; ++a0i)
#pragma unroll
    for (int a1i = 0; a1i < 3; ++a1i)
#pragma unroll
      for (int a2i = 0; a2i < 3; ++a2i) acc[a0i][a1i][a2i] = {0.f, 0.f, 0.f, 0.f};

  const char* Ap = (const char*)Apre + (size_t)bi * 65536
                   + ((4 * th + p) << 10) + lane * 16;
  const char* Bp0; const char* Bp1; const char* Bp2;
  int bstr0, bstr1, bstr2;
  {
    int y0 = i + 2 * dyb - 20;
#pragma unroll
    for (int g = 0; g < 3; ++g) {
      int y = y0 + 2 * g;
      bool v = (unsigned)y < (unsigned)H_N;
      const char* base = v ? (const char*)Bpre + (size_t)(b * H_N + y) * 98304
                           : (const char*)zchunk;
      const char* bp = base + ((4 * th + p) << 10) + lane * 16;
      int bs = v ? 12288 : 0;
      if (g == 0) { Bp0 = bp; bstr0 = bs; }
      else if (g == 1) { Bp1 = bp; bstr1 = bs; }
      else { Bp2 = bp; bstr2 = bs; }
    }
  }

  DECL_FRAGS(fA);
  DECL_FRAGS(fB);

  // 2-deep register pipeline over 8 chunks; loads issue before prior chunk's MFMAs
  LOADF(fA, 0);
  LOADF(fB, 1);
  COMPUTE(fA);
  LOADF(fA, 2);
  COMPUTE(fB);
  LOADF(fB, 3);
  COMPUTE(fA);
  LOADF(fA, 4);
  COMPUTE(fB);
  LOADF(fB, 5);
  COMPUTE(fA);
  LOADF(fA, 6);
  COMPUTE(fB);
  LOADF(fB, 7);
  COMPUTE(fA);
  COMPUTE(fB);

  // ---- epilogue: band-extract via LDS, coalesced stores
#pragma unroll
  for (int g = 0; g < 3; ++g) {
    __syncthreads();
#pragma unroll
    for (int tt = 0; tt < 2; ++tt) {
      int t = 2 * th + tt;
#pragma unroll
      for (int dl = 0; dl < 3; ++dl) {
#pragma unroll
        for (int r = 0; r < 4; ++r) {
          int a_ = kg * 4 + r;               // row within tile
          int dxi = 16 * dl + m - a_;        // col n = m
          if (dxi >= 0 && dxi <= 20) {
            int j = 2 * (16 * t + a_) + p;
            outl[dxi][j] = acc[tt][g][dl][r];
          }
        }
      }
    }
    __syncthreads();
    int dyi = dyb + g;
    size_t obase = ((size_t)(b * NK + dyi * ND) * H_N + i) * W_N;
    for (int idx = tid; idx < ND * W_N; idx += 256) {
      int dxi = idx >> 7, j = idx & 127;
      out[obase + (size_t)dxi * (H_N * W_N) + j] = outl[dxi][j];
    }
  }
}

// ---------------- fallback (only if workspace too small) ----------------
__global__ void corr_naive(const float* __restrict__ in1, const float* __restrict__ in2,
                           float* __restrict__ out) {
  size_t o = (size_t)blockIdx.x * 256 + threadIdx.x;
  const size_t total = (size_t)B_N * NK * H_N * W_N;
  if (o >= total) return;
  int j = o & 127;
  int i = (int)((o >> 7) % H_N);
  int k = (int)((o / ((size_t)H_N * W_N)) % NK);
  int b = (int)(o / ((size_t)NK * H_N * W_N));
  int dyi = k / ND, dxi = k % ND;
  int y = i + 2 * dyi - 20, x = j + 2 * dxi - 20;
  float s = 0.f;
  if ((unsigned)y < (unsigned)H_N && (unsigned)x < (unsigned)W_N) {
    const float* p1 = in1 + ((size_t)b * C_N * H_N + i) * W_N + j;
    const float* p2 = in2 + ((size_t)b * C_N * H_N + y) * W_N + x;
    for (int c = 0; c < C_N; ++c)
      s += p1[(size_t)c * H_N * W_N] * p2[(size_t)c * H_N * W_N];
  }
  out[o] = s;
}

extern "C" void kernel_launch(void* const* d_in, const int* in_sizes, int n_in,
                              void* d_out, int out_size, void* d_ws, size_t ws_size,
                              hipStream_t stream) {
  const float* in1 = (const float*)d_in[0];
  const float* in2 = (const float*)d_in[1];
  float* out = (float*)d_out;

  const size_t A_BYTES = (size_t)6144 * 8192;    // 50,331,648
  const size_t B_BYTES = (size_t)6144 * 12288;   // 75,497,472
  if (ws_size < A_BYTES + B_BYTES) {
    size_t total = (size_t)B_N * NK * H_N * W_N;
    corr_naive<<<(int)((total + 255) / 256), 256, 0, stream>>>(in1, in2, out);
    return;
  }
  unsigned short* Apre = (unsigned short*)d_ws;
  unsigned short* Bpre = (unsigned short*)((char*)d_ws + A_BYTES);

  prep<<<12288, 256, 0, stream>>>(in1, in2, Apre, Bpre);
  corr_main<<<5376, 256, 0, stream>>>(Apre, Bpre, out);
}

// Round 6
// 195.342 us; speedup vs baseline: 1.0754x; 1.0754x over previous
//
#include <hip/hip_runtime.h>
#include <stdint.h>

#define B_N   8
#define C_N   256
#define H_N   96
#define W_N   128
#define NCK   8          // C_N / 32
#define ND    21
#define NK    (ND * ND)  // 441

typedef __attribute__((ext_vector_type(8))) short short8;
typedef __attribute__((ext_vector_type(4))) float f32x4;

// 12-KB zero block (.bss) for OOB dy rows
__device__ char zchunk[12288];

__device__ __forceinline__ uint32_t f2bf(float f) {
  uint32_t u = __builtin_bit_cast(uint32_t, f);
  return (u + 0x7fffu + ((u >> 16) & 1u)) >> 16;   // RNE
}
__device__ __forceinline__ uint32_t packbf(float lo, float hi) {
  return f2bf(lo) | (f2bf(hi) << 16);
}

// ---------------- merged prepass: fp32 NCHW -> bf16 fragment-linear layouts ----------------
__global__ __launch_bounds__(256) void prep(const float* __restrict__ in1,
                                            const float* __restrict__ in2,
                                            unsigned short* __restrict__ Apre,
                                            unsigned short* __restrict__ Bpre) {
  __shared__ float tile[32][W_N + 1];
  int blk = blockIdx.x;
  bool isA = blk < 6144;
  int rblk = isA ? blk : blk - 6144;
  int ck = rblk & 7, bi = rblk >> 3;
  int b = bi / H_N, row = bi % H_N;
  const float* src = (isA ? in1 : in2) + ((size_t)(b * C_N + ck * 32) * H_N + row) * W_N;
  int tid = threadIdx.x;
  for (int idx = tid; idx < 32 * W_N; idx += 256) {
    int c = idx >> 7, j = idx & 127;
    tile[c][j] = src[(size_t)c * (H_N * W_N) + j];
  }
  __syncthreads();
  if (isA) {
    uint32_t* dst = (uint32_t*)Apre + (size_t)rblk * 2048;
    for (int q = tid; q < 2048; q += 256) {
      int e2 = q & 3, ln = (q >> 2) & 63, tp = q >> 8;
      int t = tp >> 1, p = tp & 1;
      int m = ln & 15, kg = ln >> 4;
      int c0 = kg * 8 + 2 * e2;
      int j = 32 * t + 2 * m + p;
      dst[q] = packbf(tile[c0][j], tile[c0 + 1][j]);
    }
  } else {
    uint32_t* dst = (uint32_t*)Bpre + (size_t)rblk * 3072;
    for (int q = tid; q < 3072; q += 256) {
      int e2 = q & 3, ln = (q >> 2) & 63, sp = q >> 8;
      int s = sp >> 1, p = sp & 1;
      int m = ln & 15, kg = ln >> 4;
      int c0 = kg * 8 + 2 * e2;
      int x = 32 * s + 2 * m - 20 + p;
      dst[q] = ((unsigned)x < 128u) ? packbf(tile[c0][x], tile[c0 + 1][x]) : 0u;
    }
  }
}

// ---- fragment set: one chunk's worth of MFMA operands (56 VGPR) ----
#define DECL_FRAGS(F) short8 F##_a0, F##_a1, F##_bb0, F##_bb1, F##_bb2, F##_bb3, \
                             F##_bb4, F##_bb5, F##_bb6, F##_bb7, F##_bb8, F##_bb9, F##_bb10, F##_bb11

#define LOADF(F, CK) do {                                                        \
  F##_a0 = *(const short8*)(Ap + (size_t)(CK) * 8192);                           \
  F##_a1 = *(const short8*)(Ap + (size_t)(CK) * 8192 + 2048);                    \
  F##_bb0  = *(const short8*)(Bp0 + (size_t)(CK) * bstr0 + 0 * 2048);            \
  F##_bb1  = *(const short8*)(Bp1 + (size_t)(CK) * bstr1 + 0 * 2048);            \
  F##_bb2  = *(const short8*)(Bp2 + (size_t)(CK) * bstr2 + 0 * 2048);            \
  F##_bb3  = *(const short8*)(Bp0 + (size_t)(CK) * bstr0 + 1 * 2048);            \
  F##_bb4  = *(const short8*)(Bp1 + (size_t)(CK) * bstr1 + 1 * 2048);            \
  F##_bb5  = *(const short8*)(Bp2 + (size_t)(CK) * bstr2 + 1 * 2048);            \
  F##_bb6  = *(const short8*)(Bp0 + (size_t)(CK) * bstr0 + 2 * 2048);            \
  F##_bb7  = *(const short8*)(Bp1 + (size_t)(CK) * bstr1 + 2 * 2048);            \
  F##_bb8  = *(const short8*)(Bp2 + (size_t)(CK) * bstr2 + 2 * 2048);            \
  F##_bb9  = *(const short8*)(Bp0 + (size_t)(CK) * bstr0 + 3 * 2048);            \
  F##_bb10 = *(const short8*)(Bp1 + (size_t)(CK) * bstr1 + 3 * 2048);            \
  F##_bb11 = *(const short8*)(Bp2 + (size_t)(CK) * bstr2 + 3 * 2048);            \
} while (0)

#define MF(a, b, c) __builtin_amdgcn_mfma_f32_16x16x32_bf16(a, b, c, 0, 0, 0)
// 18 MFMAs: acc[tt][g][delta], delta = ss - tt, B frag index = ss*3+g
#define COMPUTE(F) do {                                                          \
  acc[0][0][0] = MF(F##_a0, F##_bb0,  acc[0][0][0]);                             \
  acc[0][1][0] = MF(F##_a0, F##_bb1,  acc[0][1][0]);                             \
  acc[0][2][0] = MF(F##_a0, F##_bb2,  acc[0][2][0]);                             \
  acc[0][0][1] = MF(F##_a0, F##_bb3,  acc[0][0][1]);                             \
  acc[1][0][0] = MF(F##_a1, F##_bb3,  acc[1][0][0]);                             \
  acc[0][1][1] = MF(F##_a0, F##_bb4,  acc[0][1][1]);                             \
  acc[1][1][0] = MF(F##_a1, F##_bb4,  acc[1][1][0]);                             \
  acc[0][2][1] = MF(F##_a0, F##_bb5,  acc[0][2][1]);                             \
  acc[1][2][0] = MF(F##_a1, F##_bb5,  acc[1][2][0]);                             \
  acc[0][0][2] = MF(F##_a0, F##_bb6,  acc[0][0][2]);                             \
  acc[1][0][1] = MF(F##_a1, F##_bb6,  acc[1][0][1]);                             \
  acc[0][1][2] = MF(F##_a0, F##_bb7,  acc[0][1][2]);                             \
  acc[1][1][1] = MF(F##_a1, F##_bb7,  acc[1][1][1]);                             \
  acc[0][2][2] = MF(F##_a0, F##_bb8,  acc[0][2][2]);                             \
  acc[1][2][1] = MF(F##_a1, F##_bb8,  acc[1][2][1]);                             \
  acc[1][0][2] = MF(F##_a1, F##_bb9,  acc[1][0][2]);                             \
  acc[1][1][2] = MF(F##_a1, F##_bb10, acc[1][1][2]);                             \
  acc[1][2][2] = MF(F##_a1, F##_bb11, acc[1][2][2]);                             \
} while (0)

// scheduling fence: forbids the compiler from sinking next-chunk loads past this
// point (the R4 failure mode) — forces the 2-deep register pipeline to stay live.
#define SB() __builtin_amdgcn_sched_barrier(0)

// ---------------- main: barrier-free, sched_barrier-pinned register pipeline ----------
__global__ __launch_bounds__(256, 1) void corr_main(const unsigned short* __restrict__ Apre,
                                                    const unsigned short* __restrict__ Bpre,
                                                    float* __restrict__ out) {
  __shared__ float outl[ND][W_N + 1];   // 10836 B epilogue buffer

  int h = blockIdx.x;
  int l = (h & 7) * 672 + (h >> 3);     // XCD-chunked remap (5376 = 8*672, bijective)
  int c = l / 7, q = l - 7 * c;         // chain, position (chain keeps B rows identical)
  int b = c / 96, i0 = c - 96 * b;
  int gidx = 6 - q;
  int i = i0 + 6 * q; if (i >= H_N) i -= H_N;
  int bi = b * H_N + i;
  int dyb = gidx * 3;

  int tid = threadIdx.x;
  int lane = tid & 63, w = tid >> 6;    // 4 waves: (parity p, t-half th)
  int p = w & 1, th = w >> 1;
  int m = lane & 15, kg = lane >> 4;

  f32x4 acc[2][3][3];
#pragma unroll
  for (int a0i = 0; a0i < 2; ++a0i)
#pragma unroll
    for (int a1i = 0; a1i < 3; ++a1i)
#pragma unroll
      for (int a2i = 0; a2i < 3; ++a2i) acc[a0i][a1i][a2i] = {0.f, 0.f, 0.f, 0.f};

  const char* Ap = (const char*)Apre + (size_t)bi * 65536
                   + ((4 * th + p) << 10) + lane * 16;
  const char* Bp0; const char* Bp1; const char* Bp2;
  int bstr0, bstr1, bstr2;
  {
    int y0 = i + 2 * dyb - 20;
#pragma unroll
    for (int g = 0; g < 3; ++g) {
      int y = y0 + 2 * g;
      bool v = (unsigned)y < (unsigned)H_N;
      const char* base = v ? (const char*)Bpre + (size_t)(b * H_N + y) * 98304
                           : (const char*)zchunk;
      const char* bp = base + ((4 * th + p) << 10) + lane * 16;
      int bs = v ? 12288 : 0;
      if (g == 0) { Bp0 = bp; bstr0 = bs; }
      else if (g == 1) { Bp1 = bp; bstr1 = bs; }
      else { Bp2 = bp; bstr2 = bs; }
    }
  }

  DECL_FRAGS(fA);
  DECL_FRAGS(fB);

  // 2-deep register pipeline over 8 chunks, slot boundaries pinned by SB().
  // Slot k: { COMPUTE(set k) , issue LOADF(set k+2) } — while computing k,
  // set k+1's 14 KB stay in flight (compiler emits counted vmcnt(14)).
  LOADF(fA, 0);
  LOADF(fB, 1);
  SB();
  COMPUTE(fA);
  LOADF(fA, 2);
  SB();
  COMPUTE(fB);
  LOADF(fB, 3);
  SB();
  COMPUTE(fA);
  LOADF(fA, 4);
  SB();
  COMPUTE(fB);
  LOADF(fB, 5);
  SB();
  COMPUTE(fA);
  LOADF(fA, 6);
  SB();
  COMPUTE(fB);
  LOADF(fB, 7);
  SB();
  COMPUTE(fA);
  SB();
  COMPUTE(fB);

  // ---- epilogue: band-extract via LDS, coalesced stores
#pragma unroll
  for (int g = 0; g < 3; ++g) {
    __syncthreads();
#pragma unroll
    for (int tt = 0; tt < 2; ++tt) {
      int t = 2 * th + tt;
#pragma unroll
      for (int dl = 0; dl < 3; ++dl) {
#pragma unroll
        for (int r = 0; r < 4; ++r) {
          int a_ = kg * 4 + r;               // row within tile
          int dxi = 16 * dl + m - a_;        // col n = m
          if (dxi >= 0 && dxi <= 20) {
            int j = 2 * (16 * t + a_) + p;
            outl[dxi][j] = acc[tt][g][dl][r];
          }
        }
      }
    }
    __syncthreads();
    int dyi = dyb + g;
    size_t obase = ((size_t)(b * NK + dyi * ND) * H_N + i) * W_N;
    for (int idx = tid; idx < ND * W_N; idx += 256) {
      int dxi = idx >> 7, j = idx & 127;
      out[obase + (size_t)dxi * (H_N * W_N) + j] = outl[dxi][j];
    }
  }
}

// ---------------- fallback (only if workspace too small) ----------------
__global__ void corr_naive(const float* __restrict__ in1, const float* __restrict__ in2,
                           float* __restrict__ out) {
  size_t o = (size_t)blockIdx.x * 256 + threadIdx.x;
  const size_t total = (size_t)B_N * NK * H_N * W_N;
  if (o >= total) return;
  int j = o & 127;
  int i = (int)((o >> 7) % H_N);
  int k = (int)((o / ((size_t)H_N * W_N)) % NK);
  int b = (int)(o / ((size_t)NK * H_N * W_N));
  int dyi = k / ND, dxi = k % ND;
  int y = i + 2 * dyi - 20, x = j + 2 * dxi - 20;
  float s = 0.f;
  if ((unsigned)y < (unsigned)H_N && (unsigned)x < (unsigned)W_N) {
    const float* p1 = in1 + ((size_t)b * C_N * H_N + i) * W_N + j;
    const float* p2 = in2 + ((size_t)b * C_N * H_N + y) * W_N + x;
    for (int c = 0; c < C_N; ++c)
      s += p1[(size_t)c * H_N * W_N] * p2[(size_t)c * H_N * W_N];
  }
  out[o] = s;
}

extern "C" void kernel_launch(void* const* d_in, const int* in_sizes, int n_in,
                              void* d_out, int out_size, void* d_ws, size_t ws_size,
                              hipStream_t stream) {
  const float* in1 = (const float*)d_in[0];
  const float* in2 = (const float*)d_in[1];
  float* out = (float*)d_out;

  const size_t A_BYTES = (size_t)6144 * 8192;    // 50,331,648
  const size_t B_BYTES = (size_t)6144 * 12288;   // 75,497,472
  if (ws_size < A_BYTES + B_BYTES) {
    size_t total = (size_t)B_N * NK * H_N * W_N;
    corr_naive<<<(int)((total + 255) / 256), 256, 0, stream>>>(in1, in2, out);
    return;
  }
  unsigned short* Apre = (unsigned short*)d_ws;
  unsigned short* Bpre = (unsigned short*)((char*)d_ws + A_BYTES);

  prep<<<12288, 256, 0, stream>>>(in1, in2, Apre, Bpre);
  corr_main<<<5376, 256, 0, stream>>>(Apre, Bpre, out);
}